// Round 7
// baseline (419.616 us; speedup 1.0000x reference)
//
#include <hip/hip_runtime.h>
#include <hip/hip_bf16.h>
#include <stdint.h>

#define N_NODES 100000
#define N_EDGES 3200000
#define F_IN    512
#define HIDDEN  64
#define NCLS    64

#define BROWS   64                  // rows per fine bucket
#define NBKT    1563                // ceil(N_NODES / BROWS)
#define CHUNK   4096                // edges per scat1 block
#define CHUNK2  2048                // edges per scat2 block (keeps fused K2 LDS at 25 KB)
#define CAP     2432                // slots per fine bucket (mean 2048 + ~8.5 sigma)
#define NCOARSE 25                  // ceil(N_NODES / 4096)
#define CAP1    135168              // slots per coarse bucket; 66*2048
#define C2BLKS  66                  // CAP1 / CHUNK2
#define OVF_CAP 8192                // overflow side-list capacity (never hit in practice)
#define SENTINEL ((int)0x80000000)
#define NZERO   (NBKT*16 + NCOARSE*16 + 16)

#define PREP_BLKS 144
#define SC1_BLKS  782               // ceil(N_EDGES / CHUNK)
#define MLP_BLKS  1563              // ceil(N_NODES / 64)
#define SC2_BLKS  (NCOARSE * C2BLKS)  // 1650

typedef float v4f __attribute__((ext_vector_type(4)));
typedef short v8s __attribute__((ext_vector_type(8)));

// fp32 -> bf16 bits, manual RNE (cold paths only)
__device__ __forceinline__ unsigned short f2bf(float f){
  unsigned u = __float_as_uint(f);
  u += 0x7fffu + ((u >> 16) & 1u);
  return (unsigned short)(u >> 16);
}
// fp32 -> bf16 via hardware convert (m240: scalar cast is the fast path)
__device__ __forceinline__ short f2bfh(float f){
  __bf16 h = (__bf16)f;
  return __builtin_bit_cast(short, h);
}
__device__ __forceinline__ float bflo(unsigned u){ return __uint_as_float(u << 16); }
__device__ __forceinline__ float bfhi(unsigned u){ return __uint_as_float(u & 0xffff0000u); }

// ---------------------------------------------------------------------------
// K1 = prep_weights (blocks [0,144)) || scat1 (blocks [144, 144+782)).
// scat1: int4/float4 edge loads; 25 coarse buckets (runs ~164 edges = 1.3 KB
// coalesced). Per-WAVE histograms + cursors (4x32) cut LDS same-address
// atomic serialization 4x in both count and placement phases; per-bucket
// runs stay contiguous (subdivided by wave in wave order).
// Payload: localrow12 << 17 | col17, val.
// ---------------------------------------------------------------------------
__global__ __launch_bounds__(256) void k1(
    const int* __restrict__ rows, const int* __restrict__ cols,
    const float* __restrict__ vals, int* __restrict__ c1cur,
    int* __restrict__ ovf_cnt, int4* __restrict__ ovf,
    int2* __restrict__ ebkt1,
    const float* __restrict__ W1, const float* __restrict__ W2,
    unsigned short* __restrict__ w1f, unsigned short* __restrict__ w2f){
  __shared__ int  wcnt[4][32];      // per-wave histogram
  __shared__ int  lcur[4][32];      // per-wave cursors (block-local pos)
  __shared__ int  lbase[32];        // global dest base minus block-local prefix
  __shared__ int2 stage[CHUNK];     // 32 KB
  __shared__ int  sdst[CHUNK];      // 16 KB
  int t = threadIdx.x;
  int w = t >> 6;

  if (blockIdx.x < PREP_BLKS){
    int g = blockIdx.x * 256 + t;
    if (g < 16*4*64*8){
      int j = g & 7, lane = (g >> 3) & 63, nt = (g >> 9) & 3, ks = g >> 11;
      int m = lane & 15, q = lane >> 4;
      int k = ks*32 + q*8 + j, n = nt*16 + m;
      w1f[g] = f2bf(W1[k*HIDDEN + n]);
    } else {
      int u = g - 16*4*64*8;
      if (u < 2*4*64*8){
        int j = u & 7, lane = (u >> 3) & 63, nt = (u >> 9) & 3, ks = u >> 11;
        int m = lane & 15, q = lane >> 4;
        int k = ks*32 + q*8 + j, n = nt*16 + m;
        w2f[u] = f2bf(W2[k*NCLS + n]);
      }
    }
    return;
  }

  int base = (blockIdx.x - PREP_BLKS) * CHUNK;
  int cnt  = min(CHUNK, N_EDGES - base);   // always a multiple of 4
  int nv   = cnt >> 2;
  const int4*   rv = (const int4*)(rows + base);
  const int4*   cv = (const int4*)(cols + base);
  const float4* fv = (const float4*)(vals + base);

  if (t < 128) wcnt[t >> 5][t & 31] = 0;
  __syncthreads();

  int4 rr[4];
  #pragma unroll
  for (int j = 0; j < 4; ++j){
    int li4 = t + j*256;
    if (li4 < nv){
      rr[j] = rv[li4];
      atomicAdd(&wcnt[w][rr[j].x >> 12], 1);
      atomicAdd(&wcnt[w][rr[j].y >> 12], 1);
      atomicAdd(&wcnt[w][rr[j].z >> 12], 1);
      atomicAdd(&wcnt[w][rr[j].w >> 12], 1);
    } else {
      rr[j].x = rr[j].y = rr[j].z = rr[j].w = -1;
    }
  }
  __syncthreads();

  if (t < 32){
    int c0 = wcnt[0][t], c1 = wcnt[1][t], c2 = wcnt[2][t], c3 = wcnt[3][t];
    int cme = c0 + c1 + c2 + c3;
    int v = cme;
    #pragma unroll
    for (int o = 1; o < 32; o <<= 1){
      int u = __shfl_up(v, o);
      if (t >= o) v += u;
    }
    int excl = v - cme;
    if (cme){
      int g = atomicAdd(&c1cur[t*16], cme);
      lbase[t] = t*CAP1 + g - excl;
    }
    lcur[0][t] = excl;
    lcur[1][t] = excl + c0;
    lcur[2][t] = excl + c0 + c1;
    lcur[3][t] = excl + c0 + c1 + c2;
  }
  __syncthreads();

  #pragma unroll
  for (int j = 0; j < 4; ++j){
    int li4 = t + j*256;
    if (li4 < nv){
      int4   cc = cv[li4];
      float4 vf = fv[li4];
      int   rs[4] = {rr[j].x, rr[j].y, rr[j].z, rr[j].w};
      int   cs[4] = {cc.x, cc.y, cc.z, cc.w};
      float vs[4] = {vf.x, vf.y, vf.z, vf.w};
      #pragma unroll
      for (int c = 0; c < 4; ++c){
        int b  = rs[c] >> 12;
        int pos = atomicAdd(&lcur[w][b], 1);
        int dest = lbase[b] + pos;
        if (dest < b*CAP1 + CAP1){
          stage[pos] = make_int2(((rs[c] & 4095) << 17) | cs[c], __float_as_int(vs[c]));
          sdst[pos]  = lbase[b];
        } else {
          sdst[pos] = SENTINEL;
          int o = atomicAdd(ovf_cnt, 1);
          if (o < OVF_CAP) ovf[o] = make_int4(rs[c], cs[c], __float_as_int(vs[c]), 0);
        }
      }
    }
  }
  __syncthreads();

  for (int j = t; j < cnt; j += 256){
    int d = sdst[j];
    if (d != SENTINEL) ebkt1[d + j] = stage[j];
  }
}

// ---------------------------------------------------------------------------
// K2 = mlp (blocks [0,1563)) || scat2 (blocks [1563, 1563+1650)).
// Shared memory is a 25 KB union. mlp and scat2 are data-independent; the
// fusion rides scat2's 51 MB of traffic under mlp's BW-bound 205 MB X read.
// ---------------------------------------------------------------------------
__global__ __launch_bounds__(256) void k2(
    const float* __restrict__ X, const float* __restrict__ b1,
    const float* __restrict__ b2,
    const unsigned short* __restrict__ w1f, const unsigned short* __restrict__ w2f,
    unsigned short* __restrict__ logits,
    const int* __restrict__ c1cur, const int2* __restrict__ ebkt1,
    int* __restrict__ bcur, int* __restrict__ ovf_cnt, int4* __restrict__ ovf,
    int2* __restrict__ ebkt){
  __shared__ __align__(16) char smem[25088];
  int tid = threadIdx.x;

  if (blockIdx.x < MLP_BLKS){
    // ---------------- MLP: logits(bf16) = relu(X@W1+b1)@W2+b2 --------------
    float (*lds)[16][68] = (float (*)[16][68])smem;
    int wid  = tid >> 6, lane = tid & 63;
    int m    = lane & 15, q = lane >> 4;
    int base = blockIdx.x * 64 + wid * 16;
    if (base > N_NODES - 16) base = N_NODES - 16;   // tail waves redo last tile (benign)

    const float* rp = X + (size_t)(base + m) * F_IN + q * 8;
    const v8s* w1v = (const v8s*)w1f;
    const v8s* w2v = (const v8s*)w2f;

    v4f a0c = {0,0,0,0}, a1c = {0,0,0,0}, a2c = {0,0,0,0}, a3c = {0,0,0,0};
    #pragma unroll
    for (int ks = 0; ks < 16; ++ks){
      const float4* pa = (const float4*)(rp + ks * 32);
      float4 x0 = pa[0], x1 = pa[1];
      v8s af;
      af[0]=f2bfh(x0.x); af[1]=f2bfh(x0.y); af[2]=f2bfh(x0.z); af[3]=f2bfh(x0.w);
      af[4]=f2bfh(x1.x); af[5]=f2bfh(x1.y); af[6]=f2bfh(x1.z); af[7]=f2bfh(x1.w);
      a0c = __builtin_amdgcn_mfma_f32_16x16x32_bf16(af, w1v[(ks*4+0)*64 + lane], a0c, 0,0,0);
      a1c = __builtin_amdgcn_mfma_f32_16x16x32_bf16(af, w1v[(ks*4+1)*64 + lane], a1c, 0,0,0);
      a2c = __builtin_amdgcn_mfma_f32_16x16x32_bf16(af, w1v[(ks*4+2)*64 + lane], a2c, 0,0,0);
      a3c = __builtin_amdgcn_mfma_f32_16x16x32_bf16(af, w1v[(ks*4+3)*64 + lane], a3c, 0,0,0);
    }

    float b1v0 = b1[m], b1v1 = b1[16+m], b1v2 = b1[32+m], b1v3 = b1[48+m];
    #pragma unroll
    for (int r = 0; r < 4; ++r){
      int row = q*4 + r;
      lds[wid][row][     m] = fmaxf(a0c[r] + b1v0, 0.f);
      lds[wid][row][16 + m] = fmaxf(a1c[r] + b1v1, 0.f);
      lds[wid][row][32 + m] = fmaxf(a2c[r] + b1v2, 0.f);
      lds[wid][row][48 + m] = fmaxf(a3c[r] + b1v3, 0.f);
    }
    __syncthreads();

    v4f c0 = {0,0,0,0}, c1 = {0,0,0,0}, c2 = {0,0,0,0}, c3 = {0,0,0,0};
    #pragma unroll
    for (int k2i = 0; k2i < 2; ++k2i){
      const float4* ph = (const float4*)&lds[wid][m][k2i*32 + q*8];
      float4 h0 = ph[0], h1 = ph[1];
      v8s af;
      af[0]=f2bfh(h0.x); af[1]=f2bfh(h0.y); af[2]=f2bfh(h0.z); af[3]=f2bfh(h0.w);
      af[4]=f2bfh(h1.x); af[5]=f2bfh(h1.y); af[6]=f2bfh(h1.z); af[7]=f2bfh(h1.w);
      c0 = __builtin_amdgcn_mfma_f32_16x16x32_bf16(af, w2v[(k2i*4+0)*64 + lane], c0, 0,0,0);
      c1 = __builtin_amdgcn_mfma_f32_16x16x32_bf16(af, w2v[(k2i*4+1)*64 + lane], c1, 0,0,0);
      c2 = __builtin_amdgcn_mfma_f32_16x16x32_bf16(af, w2v[(k2i*4+2)*64 + lane], c2, 0,0,0);
      c3 = __builtin_amdgcn_mfma_f32_16x16x32_bf16(af, w2v[(k2i*4+3)*64 + lane], c3, 0,0,0);
    }

    float b2v0 = b2[m], b2v1 = b2[16+m], b2v2 = b2[32+m], b2v3 = b2[48+m];
    unsigned short* lp = logits + (size_t)base * NCLS;
    #pragma unroll
    for (int r = 0; r < 4; ++r){
      int row = q*4 + r;
      lp[row*NCLS +      m] = (unsigned short)f2bfh(c0[r] + b2v0);
      lp[row*NCLS + 16 + m] = (unsigned short)f2bfh(c1[r] + b2v1);
      lp[row*NCLS + 32 + m] = (unsigned short)f2bfh(c2[r] + b2v2);
      lp[row*NCLS + 48 + m] = (unsigned short)f2bfh(c3[r] + b2v3);
    }
    return;
  }

  // ------------- scat2: coarse region chunk -> 64 nested fine buckets ------
  int2* stage = (int2*)smem;               // 16384 B
  int*  sdst  = (int*)(smem + 16384);      //  8192 B
  int*  lcnt  = (int*)(smem + 24576);      //   256 B
  int*  lbase = (int*)(smem + 24832);      //   256 B
  int sbid = blockIdx.x - MLP_BLKS;
  int c  = sbid / C2BLKS;
  int k0 = sbid % C2BLKS;

  int cntc = c1cur[c*16];
  if (cntc > CAP1) cntc = CAP1;
  int start = k0 * CHUNK2;
  if (start >= cntc) return;                 // uniform across block
  int cnt = min(CHUNK2, cntc - start);
  const int2* src = ebkt1 + (size_t)c * CAP1 + start;

  if (tid < 64) lcnt[tid] = 0;
  __syncthreads();

  int2 ev[8];
  #pragma unroll
  for (int k = 0; k < 8; ++k){
    int li = tid + k*256;
    if (li < cnt){
      ev[k] = src[li];
      atomicAdd(&lcnt[(((unsigned)ev[k].x) >> 17) >> 6], 1);
    } else ev[k].x = -1;
  }
  __syncthreads();

  if (tid < 64){
    int cme = lcnt[tid];
    int v = cme;
    #pragma unroll
    for (int o = 1; o < 64; o <<= 1){
      int u = __shfl_up(v, o);
      if (tid >= o) v += u;
    }
    int excl = v - cme;
    if (cme){
      int gb = c*64 + tid;                   // global fine bucket
      int g = atomicAdd(&bcur[gb*16], cme);
      lbase[tid] = gb*CAP + g - excl;
    }
    lcnt[tid] = excl;
  }
  __syncthreads();

  #pragma unroll
  for (int k = 0; k < 8; ++k){
    if (ev[k].x >= 0){
      unsigned x = (unsigned)ev[k].x;
      int lr12 = (int)(x >> 17);
      int fb   = lr12 >> 6;
      int pos = atomicAdd(&lcnt[fb], 1);
      int dest = lbase[fb] + pos;
      if (dest < (c*64 + fb)*CAP + CAP){
        stage[pos] = make_int2(((lr12 & 63) << 17) | (int)(x & 0x1FFFFu), ev[k].y);
        sdst[pos]  = lbase[fb];
      } else {
        sdst[pos] = SENTINEL;
        int o = atomicAdd(ovf_cnt, 1);
        if (o < OVF_CAP) ovf[o] = make_int4(c*4096 + lr12, (int)(x & 0x1FFFFu), ev[k].y, 0);
      }
    }
  }
  __syncthreads();

  for (int j = tid; j < cnt; j += 256){
    int d = sdst[j];
    if (d != SENTINEL) ebkt[d + j] = stage[j];
  }
}

// ---------------------------------------------------------------------------
// K3: fused counting-sort + aggregate. Single global read of ebkt (reg-staged
// count). Gather restructured to uint4: 8 lanes per logits row -> 8 edges per
// vmem instruction (2x fewer gather + ds-read instructions, same bytes/FMA).
// 3-level shfl reduce; lanes 0..7 store 32 B each (full 256 B row).
// ---------------------------------------------------------------------------
__global__ __launch_bounds__(256) void bucket_agg(
    const int* __restrict__ bcur, const int2* __restrict__ ebkt,
    const unsigned short* __restrict__ logits, float* __restrict__ out,
    const int* __restrict__ ovf_cnt, const int4* __restrict__ ovfl){
  __shared__ int2 sorted[CAP];        // 19456 B
  __shared__ int  rc[BROWS];
  __shared__ int  rbase[BROWS + 1];
  __shared__ int  rcur[BROWS];
  int b = blockIdx.x, t = threadIdx.x;
  int w = t >> 6, lane = t & 63;
  int h = lane & 7, sel = lane >> 3;    // 8 lanes/row, 8 edges/instruction

  if (t < BROWS) rc[t] = 0;
  __syncthreads();

  int cnt = bcur[b * 16];
  if (cnt > CAP) cnt = CAP;
  const int2* ep = ebkt + (size_t)b * CAP;
  int ocnt = ovf_cnt[0];
  if (ocnt > OVF_CAP) ocnt = OVF_CAP;

  // single pass: load to regs + count (CAP/256 = 9.5 -> 10 static slots)
  int2 ev[10];
  #pragma unroll
  for (int k = 0; k < 10; ++k){
    int j = t + k*256;
    if (j < cnt){
      ev[k] = ep[j];
      atomicAdd(&rc[((unsigned)ev[k].x) >> 17], 1);
    } else ev[k].x = -1;
  }
  __syncthreads();

  if (t < BROWS){
    int c = rc[t];
    int v = c;
    #pragma unroll
    for (int o = 1; o < 64; o <<= 1){
      int u = __shfl_up(v, o);
      if (lane >= o) v += u;
    }
    rbase[t + 1] = v;
    rcur[t]      = v - c;
    if (t == 0) rbase[0] = 0;
  }
  __syncthreads();

  #pragma unroll
  for (int k = 0; k < 10; ++k){
    if (ev[k].x >= 0){
      int pos = atomicAdd(&rcur[((unsigned)ev[k].x) >> 17], 1);
      sorted[pos] = ev[k];
    }
  }
  __syncthreads();

  const uint4* lg4 = (const uint4*)logits;   // 8 uint4 per node row
  int row0 = b * BROWS;
  for (int n = w; n < BROWS; n += 4){
    int node = row0 + n;
    if (node >= N_NODES) break;
    int s = rbase[n], e = rbase[n + 1];
    float a0=0.f,a1=0.f,a2=0.f,a3=0.f,a4=0.f,a5=0.f,a6=0.f,a7=0.f;
    int i = s;
    for (; i + 16 <= e; i += 16){
      int2 e0 = sorted[i     + sel];
      int2 e1 = sorted[i + 8 + sel];
      uint4 u0 = lg4[((size_t)(e0.x & 0x1FFFF) << 3) + h];
      uint4 u1 = lg4[((size_t)(e1.x & 0x1FFFF) << 3) + h];
      float v0 = __int_as_float(e0.y), v1 = __int_as_float(e1.y);
      a0 = fmaf(v0, bflo(u0.x), a0); a1 = fmaf(v0, bfhi(u0.x), a1);
      a2 = fmaf(v0, bflo(u0.y), a2); a3 = fmaf(v0, bfhi(u0.y), a3);
      a4 = fmaf(v0, bflo(u0.z), a4); a5 = fmaf(v0, bfhi(u0.z), a5);
      a6 = fmaf(v0, bflo(u0.w), a6); a7 = fmaf(v0, bfhi(u0.w), a7);
      a0 = fmaf(v1, bflo(u1.x), a0); a1 = fmaf(v1, bfhi(u1.x), a1);
      a2 = fmaf(v1, bflo(u1.y), a2); a3 = fmaf(v1, bfhi(u1.y), a3);
      a4 = fmaf(v1, bflo(u1.z), a4); a5 = fmaf(v1, bfhi(u1.z), a5);
      a6 = fmaf(v1, bflo(u1.w), a6); a7 = fmaf(v1, bfhi(u1.w), a7);
    }
    for (; i < e; i += 8){
      int idx = i + sel;
      int col = 0; float v = 0.f;
      if (idx < e){ int2 evv = sorted[idx]; col = evv.x & 0x1FFFF; v = __int_as_float(evv.y); }
      uint4 u = lg4[((size_t)col << 3) + h];
      a0 = fmaf(v, bflo(u.x), a0); a1 = fmaf(v, bfhi(u.x), a1);
      a2 = fmaf(v, bflo(u.y), a2); a3 = fmaf(v, bfhi(u.y), a3);
      a4 = fmaf(v, bflo(u.z), a4); a5 = fmaf(v, bfhi(u.z), a5);
      a6 = fmaf(v, bflo(u.w), a6); a7 = fmaf(v, bfhi(u.w), a7);
    }
    a0 += __shfl_xor(a0, 8); a0 += __shfl_xor(a0, 16); a0 += __shfl_xor(a0, 32);
    a1 += __shfl_xor(a1, 8); a1 += __shfl_xor(a1, 16); a1 += __shfl_xor(a1, 32);
    a2 += __shfl_xor(a2, 8); a2 += __shfl_xor(a2, 16); a2 += __shfl_xor(a2, 32);
    a3 += __shfl_xor(a3, 8); a3 += __shfl_xor(a3, 16); a3 += __shfl_xor(a3, 32);
    a4 += __shfl_xor(a4, 8); a4 += __shfl_xor(a4, 16); a4 += __shfl_xor(a4, 32);
    a5 += __shfl_xor(a5, 8); a5 += __shfl_xor(a5, 16); a5 += __shfl_xor(a5, 32);
    a6 += __shfl_xor(a6, 8); a6 += __shfl_xor(a6, 16); a6 += __shfl_xor(a6, 32);
    a7 += __shfl_xor(a7, 8); a7 += __shfl_xor(a7, 16); a7 += __shfl_xor(a7, 32);
    if (sel == 0){
      if (ocnt){                       // overflow fix-up (empty in practice)
        for (int j = 0; j < ocnt; ++j){
          int4 eo = ovfl[j];
          if (eo.x == node){
            uint4 u = lg4[((size_t)eo.y << 3) + h];
            float v = __int_as_float(eo.z);
            a0 = fmaf(v, bflo(u.x), a0); a1 = fmaf(v, bfhi(u.x), a1);
            a2 = fmaf(v, bflo(u.y), a2); a3 = fmaf(v, bfhi(u.y), a3);
            a4 = fmaf(v, bflo(u.z), a4); a5 = fmaf(v, bfhi(u.z), a5);
            a6 = fmaf(v, bflo(u.w), a6); a7 = fmaf(v, bfhi(u.w), a7);
          }
        }
      }
      float4* op = (float4*)(out + (size_t)node * NCLS + h * 8);
      op[0] = make_float4(a0, a1, a2, a3);
      op[1] = make_float4(a4, a5, a6, a7);
    }
  }
}

// Fallback if workspace is too small: direct atomic scatter.
__global__ void scatter_atomic(const int* __restrict__ rows, const int* __restrict__ cols,
                               const float* __restrict__ vals,
                               const unsigned short* __restrict__ logits,
                               float* __restrict__ out){
  long g = (long)blockIdx.x * 256 + threadIdx.x;
  int e = (int)(g >> 6), c = (int)(g & 63);
  if (e < N_EDGES){
    float lv = __uint_as_float(((unsigned)logits[(size_t)cols[e] * NCLS + c]) << 16);
    atomicAdd(&out[(size_t)rows[e] * NCLS + c], vals[e] * lv);
  }
}

extern "C" void kernel_launch(void* const* d_in, const int* in_sizes, int n_in,
                              void* d_out, int out_size, void* d_ws, size_t ws_size,
                              hipStream_t stream){
  const float* X     = (const float*)d_in[0];
  const int*   erows = (const int*)  d_in[1];
  const int*   ecols = (const int*)  d_in[2];
  const float* evals = (const float*)d_in[3];
  const float* W1    = (const float*)d_in[4];
  const float* b1    = (const float*)d_in[5];
  const float* W2    = (const float*)d_in[6];
  const float* b2    = (const float*)d_in[7];
  float* out = (float*)d_out;

  char* ws = (char*)d_ws;
  size_t off = 0;
  auto alloc = [&](size_t bytes) -> char* {
    char* p = ws + off;
    off = (off + bytes + 255) & ~(size_t)255;
    return p;
  };
  unsigned short* logits = (unsigned short*)alloc((size_t)N_NODES * NCLS * 2); // 12.8 MB
  unsigned short* w1f    = (unsigned short*)alloc(16*4*64*8 * 2);
  unsigned short* w2f    = (unsigned short*)alloc(2*4*64*8 * 2);
  int*  bcur  = (int*)alloc((size_t)NZERO * 4);   // fine cursors | coarse cursors | ovf_cnt
  int*  c1cur = bcur + NBKT*16;
  int*  ovfc  = bcur + NBKT*16 + NCOARSE*16;
  int4* ovf   = (int4*)alloc((size_t)OVF_CAP * 16);
  int2* ebkt1 = (int2*)alloc((size_t)NCOARSE * CAP1 * 8);  // 27.0 MB coarse regions
  int2* ebkt  = (int2*)alloc((size_t)NBKT * CAP * 8);      // 30.4 MB fine regions
  size_t full_need = off;   // ~71 MB

  if (ws_size >= full_need){
    hipMemsetAsync(bcur, 0, (size_t)NZERO * 4, stream);    // ~100 KB, ~2 us
    k1<<<PREP_BLKS + SC1_BLKS, 256, 0, stream>>>(
        erows, ecols, evals, c1cur, ovfc, ovf, ebkt1, W1, W2, w1f, w2f);
    k2<<<MLP_BLKS + SC2_BLKS, 256, 0, stream>>>(
        X, b1, b2, w1f, w2f, logits, c1cur, ebkt1, bcur, ovfc, ovf, ebkt);
    bucket_agg<<<NBKT, 256, 0, stream>>>(bcur, ebkt, logits, out, ovfc, ovf);
  } else {
    // prep-only grid (prep blocks are [0, PREP_BLKS)), then mlp-only grid
    k1<<<PREP_BLKS, 256, 0, stream>>>(
        erows, ecols, evals, c1cur, ovfc, ovf, ebkt1, W1, W2, w1f, w2f);
    k2<<<MLP_BLKS, 256, 0, stream>>>(
        X, b1, b2, w1f, w2f, logits, c1cur, ebkt1, bcur, ovfc, ovf, ebkt);
    hipMemsetAsync(out, 0, (size_t)N_NODES * NCLS * 4, stream);
    scatter_atomic<<<(int)(((long)N_EDGES * 64 + 255) / 256), 256, 0, stream>>>(
        erows, ecols, evals, logits, out);
  }
}